// Round 4
// baseline (493.684 us; speedup 1.0000x reference)
//
#include <hip/hip_runtime.h>
#include <hip/hip_bf16.h>

#define TT 512
#define HIDD 2048
#define NH 16
#define NKV 8
#define DD 128
#define INTR 6144
#define SEQ 4096
#define SCALE 0.08838834764831845f

typedef __attribute__((ext_vector_type(8))) short short8;
typedef __attribute__((ext_vector_type(4))) float floatx4;

static __device__ __forceinline__ unsigned short f2b(float f) {
  unsigned int u = __float_as_uint(f);
  u += 0x7fffu + ((u >> 16) & 1u);
  return (unsigned short)(u >> 16);
}

static __device__ __forceinline__ unsigned int f2b2(float a, float b) {
  __hip_bfloat162 h = __float22bfloat162_rn(make_float2(a, b));
  return *reinterpret_cast<unsigned int*>(&h);
}

// async global->LDS, 16B per lane; dst = wave-uniform base + lane*16
static __device__ __forceinline__ void gl2lds(const void* g, void* l) {
  __builtin_amdgcn_global_load_lds((const __attribute__((address_space(1))) void*)g,
                                   (__attribute__((address_space(3))) void*)l, 16, 0, 0);
}

// ---------------- GEMM core: m97-style, global_load_lds staging, XOR-swizzled LDS ----------------
// C(64x128) += A(64x[kbeg:kend]) * B(128x[kbeg:kend])^T ; A bf16, B fp32 or bf16.
// A tile 64x32 bf16 (4KB): row=64B=4 chunks of 16B, slot(r,c) holds global chunk c^((r>>1)&3)
// B fp32 tile 128x32 (16KB): row=128B=8 chunks, swizzle c^(r&7)
// B bf16 tile 128x32 (8KB): row=64B=4 chunks, swizzle c^((r>>1)&3)
// -> fragment reads have at most 2-way bank aliasing (free).

template <bool B16>
static __device__ __forceinline__ void gemm_core64(const unsigned short* __restrict__ A, int lda,
                                                   const void* __restrict__ B, int ldb,
                                                   int kbeg, int kend, floatx4 (&acc)[2][4],
                                                   unsigned short* As, void* Bs) {
  const int tid = threadIdx.x;
  const int lane = tid & 63;
  const int wave = tid >> 6;
  // staging source pointers (per-thread, advance +32 elements per iter)
  const int ar = tid >> 2, ac = tid & 3;
  const unsigned short* aS = A + (size_t)ar * lda + ((ac ^ ((ar >> 1) & 3)) << 3) + kbeg;
  const unsigned short* bS16[2];
  const float* bS32[4];
  if (B16) {
    const unsigned short* Bh = (const unsigned short*)B;
    const int swz = (tid & 3) ^ ((tid >> 3) & 3);
#pragma unroll
    for (int j = 0; j < 2; ++j)
      bS16[j] = Bh + (size_t)((tid >> 2) + (j << 6)) * ldb + (swz << 3) + kbeg;
  } else {
    const float* Bf = (const float*)B;
    const int swz = (tid & 7) ^ ((tid >> 3) & 7);
#pragma unroll
    for (int j = 0; j < 4; ++j)
      bS32[j] = Bf + (size_t)((tid >> 3) + (j << 5)) * ldb + (swz << 2) + kbeg;
  }
  // fragment LDS addresses (loop-invariant)
  const int lrow = lane & 15, quad = lane >> 4;
  const int wr = (wave >> 1) << 5;  // 0 / 32
  const int wc = (wave & 1) << 6;   // 0 / 64
  const unsigned short* afp[2];
#pragma unroll
  for (int mi = 0; mi < 2; ++mi) {
    const int r = wr + mi * 16 + lrow;
    afp[mi] = As + r * 32 + ((quad ^ ((r >> 1) & 3)) << 3);
  }
  const unsigned short* bfp16[4];
  const float* bfpa[4];
  const float* bfpb[4];
#pragma unroll
  for (int ni = 0; ni < 4; ++ni) {
    const int n = wc + ni * 16 + lrow;
    if (B16) {
      bfp16[ni] = (const unsigned short*)Bs + n * 32 + ((quad ^ ((n >> 1) & 3)) << 3);
    } else {
      const int c0 = (quad << 1) ^ (n & 7);
      bfpa[ni] = (const float*)Bs + n * 32 + (c0 << 2);
      bfpb[ni] = (const float*)Bs + n * 32 + ((c0 ^ 1) << 2);
    }
  }
  for (int k0 = kbeg; k0 < kend; k0 += 32) {
    gl2lds(aS, As + (wave << 9));
    aS += 32;
    if (B16) {
#pragma unroll
      for (int j = 0; j < 2; ++j) {
        gl2lds(bS16[j], (unsigned short*)Bs + (wave << 9) + (j << 11));
        bS16[j] += 32;
      }
    } else {
#pragma unroll
      for (int j = 0; j < 4; ++j) {
        gl2lds(bS32[j], (float*)Bs + (wave << 8) + (j << 10));
        bS32[j] += 32;
      }
    }
    __syncthreads();  // drains vmcnt -> LDS tiles valid
    short8 af[2], bfr[4];
#pragma unroll
    for (int mi = 0; mi < 2; ++mi) af[mi] = *reinterpret_cast<const short8*>(afp[mi]);
    if (B16) {
#pragma unroll
      for (int ni = 0; ni < 4; ++ni) bfr[ni] = *reinterpret_cast<const short8*>(bfp16[ni]);
    } else {
#pragma unroll
      for (int ni = 0; ni < 4; ++ni) {
        const float4 fa = *reinterpret_cast<const float4*>(bfpa[ni]);
        const float4 fb = *reinterpret_cast<const float4*>(bfpb[ni]);
        uint4 u;
        u.x = f2b2(fa.x, fa.y); u.y = f2b2(fa.z, fa.w);
        u.z = f2b2(fb.x, fb.y); u.w = f2b2(fb.z, fb.w);
        bfr[ni] = *reinterpret_cast<short8*>(&u);
      }
    }
#pragma unroll
    for (int mi = 0; mi < 2; ++mi)
#pragma unroll
      for (int ni = 0; ni < 4; ++ni)
        acc[mi][ni] = __builtin_amdgcn_mfma_f32_16x16x32_bf16(af[mi], bfr[ni], acc[mi][ni], 0, 0, 0);
    __syncthreads();  // protect LDS before next iter's stores
  }
}

#define EPI_VARS \
  const int lane = threadIdx.x & 63; \
  const int wave = threadIdx.x >> 6; \
  const int wr = (wave >> 1) << 5;   \
  const int wc = (wave & 1) << 6;    \
  const int lrow = lane & 15;        \
  const int quad = lane >> 4;

#define ZERO_ACC \
  floatx4 acc[2][4]; \
  _Pragma("unroll") for (int mi = 0; mi < 2; ++mi) \
  _Pragma("unroll") for (int ni = 0; ni < 4; ++ni) { floatx4 z = {0.f, 0.f, 0.f, 0.f}; acc[mi][ni] = z; }

// ---------------- kernels ----------------

__global__ __launch_bounds__(1024) void k_rms1(const float* __restrict__ conv,
                                               const float* __restrict__ w,
                                               float* __restrict__ xb,
                                               unsigned short* __restrict__ h1b) {
  const int t0 = blockIdx.x << 5;
  const int tid = threadIdx.x;
  const int j = tid & 31;
  const int g = tid >> 5;
  __shared__ float part[32][32];
  __shared__ float tile[32][33];
  __shared__ float rs[32];
  float ss = 0.f;
  for (int c0 = 0; c0 < HIDD; c0 += 32) {
    const float v = conv[(size_t)(c0 + g) * TT + t0 + j];
    ss += v * v;
  }
  part[g][j] = ss;
  __syncthreads();
  if (g == 0) {
    float tot = 0.f;
#pragma unroll
    for (int q = 0; q < 32; ++q) tot += part[q][j];
    rs[j] = rsqrtf(tot * (1.0f / HIDD) + 1e-6f);
  }
  __syncthreads();
  for (int c0 = 0; c0 < HIDD; c0 += 32) {
    tile[g][j] = conv[(size_t)(c0 + g) * TT + t0 + j];
    __syncthreads();
    const float v = tile[j][g];
    const float rv = rs[g];
    xb[(size_t)(t0 + g) * HIDD + c0 + j] = v;
    h1b[(size_t)(t0 + g) * HIDD + c0 + j] = f2b(v * rv * w[c0 + j]);
    __syncthreads();
  }
}

__global__ __launch_bounds__(256) void k_gemm_qkv(const unsigned short* __restrict__ h1b,
                                                  const float* __restrict__ wq,
                                                  const float* __restrict__ wk,
                                                  const float* __restrict__ wv,
                                                  float* __restrict__ Pq) {
  __shared__ unsigned short As[64 * 32];
  __shared__ float Bsf[128 * 32];
  const int bid = blockIdx.x;       // 1024 = 8 mt x (32 nt x 4 s)
  const int mt = bid >> 7, gid = bid & 127;
  const int nt = gid >> 2, s = gid & 3;
  const int m0 = mt << 6, n0 = nt << 7;
  const float* Bp;
  if (n0 < 2048)      Bp = wq + (size_t)n0 * HIDD;
  else if (n0 < 3072) Bp = wk + (size_t)(n0 - 2048) * HIDD;
  else                Bp = wv + (size_t)(n0 - 3072) * HIDD;
  ZERO_ACC
  gemm_core64<false>(h1b + (size_t)m0 * HIDD, HIDD, Bp, HIDD, s * 512, s * 512 + 512, acc, As, Bsf);
  EPI_VARS
  float* out = Pq + (size_t)s * (TT * 4096);
#pragma unroll
  for (int mi = 0; mi < 2; ++mi)
#pragma unroll
    for (int ni = 0; ni < 4; ++ni)
#pragma unroll
      for (int rr = 0; rr < 4; ++rr) {
        const int row = m0 + wr + mi * 16 + quad * 4 + rr;
        const int col = n0 + wc + ni * 16 + lrow;
        out[(size_t)row * 4096 + col] = acc[mi][ni][rr];
      }
}

__global__ __launch_bounds__(128) void k_rope(const float* __restrict__ Pq,
                                              const float* __restrict__ cosb,
                                              const float* __restrict__ sinb,
                                              const float* __restrict__ qnw,
                                              const float* __restrict__ knw,
                                              unsigned short* __restrict__ qb,
                                              unsigned short* __restrict__ kb,
                                              unsigned short* __restrict__ vtb,
                                              float* __restrict__ kout,
                                              float* __restrict__ vout) {
  const int u = blockIdx.x;
  const int t = blockIdx.y;
  const int d = threadIdx.x;
  __shared__ float red[2];
  __shared__ float sh[DD];
  int slot;
  if (u < NH)            slot = u * DD + d;
  else if (u < NH + NKV) slot = 2048 + (u - NH) * DD + d;
  else                   slot = 3072 + (u - NH - NKV) * DD + d;
  const size_t idx = (size_t)t * 4096 + slot;
  float val = Pq[idx] + Pq[idx + TT * 4096] + Pq[idx + 2 * TT * 4096] + Pq[idx + 3 * TT * 4096];
  if (u < NH + NKV) {
    float ss = val * val;
    const int lane = d & 63, wid = d >> 6;
#pragma unroll
    for (int o = 32; o; o >>= 1) ss += __shfl_xor(ss, o);
    if (!lane) red[wid] = ss;
    __syncthreads();
    const float r = rsqrtf((red[0] + red[1]) * (1.0f / DD) + 1e-6f);
    const float w = (u < NH) ? qnw[d] : knw[d];
    const float nv = val * r * w;
    sh[d] = nv;
    __syncthreads();
    const float partner = sh[d ^ 64];
    const float rh = (d < 64) ? -partner : partner;
    const float o = nv * cosb[(size_t)t * DD + d] + rh * sinb[(size_t)t * DD + d];
    if (u < NH) {
      qb[(size_t)u * TT * DD + (size_t)t * DD + d] = f2b(o);
    } else {
      const int kh = u - NH;
      kout[(size_t)kh * SEQ * DD + (size_t)t * DD + d] = o;
      kb[(size_t)kh * TT * DD + (size_t)t * DD + d] = f2b(o);
    }
  } else {
    const int vh = u - NH - NKV;
    vout[(size_t)vh * SEQ * DD + (size_t)t * DD + d] = val;
    vtb[(size_t)vh * DD * TT + (size_t)d * TT + t] = f2b(val);
  }
}

__global__ __launch_bounds__(256) void k_tail(const float* __restrict__ kc,
                                              const float* __restrict__ vc,
                                              float* __restrict__ ko,
                                              float* __restrict__ vo) {
  const int i = blockIdx.x * 256 + threadIdx.x;
  const int e = i << 2;
  const int s = (e >> 7) & (SEQ - 1);
  if (s >= TT) {
    reinterpret_cast<float4*>(ko)[i] = reinterpret_cast<const float4*>(kc)[i];
    reinterpret_cast<float4*>(vo)[i] = reinterpret_cast<const float4*>(vc)[i];
  }
}

__global__ __launch_bounds__(256) void k_scores(const unsigned short* __restrict__ qb,
                                                const unsigned short* __restrict__ kb,
                                                float* __restrict__ sc) {
  __shared__ unsigned short As[64 * 32];
  __shared__ unsigned short Bsh[128 * 32];
  const int m0 = blockIdx.x << 6, n0 = blockIdx.y << 7, h = blockIdx.z;
  ZERO_ACC
  gemm_core64<true>(qb + (size_t)h * TT * DD + (size_t)m0 * DD, DD,
                    kb + (size_t)(h >> 1) * TT * DD + (size_t)n0 * DD, DD, 0, DD, acc, As, Bsh);
  EPI_VARS
  float* out = sc + (size_t)h * TT * TT;
#pragma unroll
  for (int mi = 0; mi < 2; ++mi)
#pragma unroll
    for (int ni = 0; ni < 4; ++ni)
#pragma unroll
      for (int rr = 0; rr < 4; ++rr) {
        const int t = m0 + wr + mi * 16 + quad * 4 + rr;
        const int s = n0 + wc + ni * 16 + lrow;
        float v = acc[mi][ni][rr] * SCALE;
        if (s > t) v += -10000.0f;
        out[(size_t)t * TT + s] = v;
      }
}

__global__ __launch_bounds__(256) void k_softmax(const float* __restrict__ sc,
                                                 unsigned short* __restrict__ Pb) {
  const int h = blockIdx.x >> 9, t = blockIdx.x & 511;
  const int tid = threadIdx.x;
  const float* row = sc + ((size_t)h * TT + t) * TT;
  float v0 = row[tid], v1 = row[tid + 256];
  __shared__ float red[4];
  const int lane = tid & 63, wid = tid >> 6;
  float m = fmaxf(v0, v1);
#pragma unroll
  for (int o = 32; o; o >>= 1) m = fmaxf(m, __shfl_xor(m, o));
  if (!lane) red[wid] = m;
  __syncthreads();
  m = fmaxf(fmaxf(red[0], red[1]), fmaxf(red[2], red[3]));
  const float e0 = __expf(v0 - m), e1 = __expf(v1 - m);
  float s = e0 + e1;
  __syncthreads();
#pragma unroll
  for (int o = 32; o; o >>= 1) s += __shfl_xor(s, o);
  if (!lane) red[wid] = s;
  __syncthreads();
  const float inv = 1.0f / (red[0] + red[1] + red[2] + red[3]);
  unsigned short* orow = Pb + ((size_t)h * TT + t) * TT;
  orow[tid] = f2b(e0 * inv);
  orow[tid + 256] = f2b(e1 * inv);
}

__global__ __launch_bounds__(256) void k_pv(const unsigned short* __restrict__ Pb,
                                            const unsigned short* __restrict__ vtb,
                                            float* __restrict__ Ppv) {
  __shared__ unsigned short As[64 * 32];
  __shared__ unsigned short Bsh[128 * 32];
  const int m0 = blockIdx.x << 6, h = blockIdx.y, s = blockIdx.z;
  ZERO_ACC
  gemm_core64<true>(Pb + (size_t)h * TT * TT + (size_t)m0 * TT, TT,
                    vtb + (size_t)(h >> 1) * DD * TT, TT, s * 128, s * 128 + 128, acc, As, Bsh);
  EPI_VARS
  float* out = Ppv + (size_t)s * (TT * HIDD);
#pragma unroll
  for (int mi = 0; mi < 2; ++mi)
#pragma unroll
    for (int ni = 0; ni < 4; ++ni)
#pragma unroll
      for (int rr = 0; rr < 4; ++rr) {
        const int row = m0 + wr + mi * 16 + quad * 4 + rr;
        const int col = wc + ni * 16 + lrow;
        out[(size_t)row * HIDD + h * DD + col] = acc[mi][ni][rr];
      }
}

__global__ __launch_bounds__(256) void k_red_pv(const float* __restrict__ Ppv,
                                                unsigned short* __restrict__ o_inb) {
  const int i = blockIdx.x * 256 + threadIdx.x;
  const float4* p = reinterpret_cast<const float4*>(Ppv);
  float4 a = p[i];
  const float4 b = p[i + 262144], c = p[i + 524288], d = p[i + 786432];
  a.x += b.x + c.x + d.x; a.y += b.y + c.y + d.y;
  a.z += b.z + c.z + d.z; a.w += b.w + c.w + d.w;
  uint2 o;
  o.x = f2b2(a.x, a.y);
  o.y = f2b2(a.z, a.w);
  *reinterpret_cast<uint2*>(o_inb + (size_t)i * 4) = o;
}

__global__ __launch_bounds__(256) void k_gemm_o(const unsigned short* __restrict__ o_inb,
                                                const float* __restrict__ wo,
                                                float* __restrict__ Po) {
  __shared__ unsigned short As[64 * 32];
  __shared__ float Bsf[128 * 32];
  const int bid = blockIdx.x;       // 1024 = 8 mt x (16 nt x 8 s)
  const int mt = bid >> 7, gid = bid & 127;
  const int nt = gid >> 3, s = gid & 7;
  const int m0 = mt << 6, n0 = nt << 7;
  ZERO_ACC
  gemm_core64<false>(o_inb + (size_t)m0 * HIDD, HIDD, wo + (size_t)n0 * HIDD, HIDD,
                     s * 256, s * 256 + 256, acc, As, Bsf);
  EPI_VARS
  float* out = Po + (size_t)s * (TT * HIDD);
#pragma unroll
  for (int mi = 0; mi < 2; ++mi)
#pragma unroll
    for (int ni = 0; ni < 4; ++ni)
#pragma unroll
      for (int rr = 0; rr < 4; ++rr) {
        const int row = m0 + wr + mi * 16 + quad * 4 + rr;
        const int col = n0 + wc + ni * 16 + lrow;
        out[(size_t)row * HIDD + col] = acc[mi][ni][rr];
      }
}

__global__ __launch_bounds__(256) void k_rms2(const float* __restrict__ xb,
                                              const float* __restrict__ Po,
                                              const float* __restrict__ w,
                                              float* __restrict__ hidden,
                                              unsigned short* __restrict__ h2b) {
  const int t = blockIdx.x;
  const int tid = threadIdx.x;
  float2 v[4];
  float ss = 0.f;
#pragma unroll
  for (int i = 0; i < 4; ++i) {
    const int c = (tid << 1) + (i << 9);
    const size_t idx = (size_t)t * HIDD + c;
    float2 a = *reinterpret_cast<const float2*>(xb + idx);
#pragma unroll
    for (int sp = 0; sp < 8; ++sp) {
      const float2 b = *reinterpret_cast<const float2*>(Po + idx + (size_t)sp * (TT * HIDD));
      a.x += b.x; a.y += b.y;
    }
    v[i] = a;
    ss += a.x * a.x + a.y * a.y;
  }
  __shared__ float red[4];
  const int lane = tid & 63, wid = tid >> 6;
#pragma unroll
  for (int o = 32; o; o >>= 1) ss += __shfl_xor(ss, o);
  if (!lane) red[wid] = ss;
  __syncthreads();
  const float tot = red[0] + red[1] + red[2] + red[3];
  const float r = rsqrtf(tot * (1.0f / HIDD) + 1e-6f);
#pragma unroll
  for (int i = 0; i < 4; ++i) {
    const int c = (tid << 1) + (i << 9);
    const size_t idx = (size_t)t * HIDD + c;
    *reinterpret_cast<float2*>(hidden + idx) = v[i];
    const float2 wv2 = *reinterpret_cast<const float2*>(w + c);
    *reinterpret_cast<unsigned int*>(h2b + idx) = f2b2(v[i].x * r * wv2.x, v[i].y * r * wv2.y);
  }
}

__global__ __launch_bounds__(256) void k_gemm_gu(const unsigned short* __restrict__ h2b,
                                                 const float* __restrict__ wgu,
                                                 float* __restrict__ gu) {
  __shared__ unsigned short As[64 * 32];
  __shared__ float Bsf[128 * 32];
  const int bid = blockIdx.x;       // 768 = 8 mt x 96 nt ; XCD = nt%8 for all mt
  const int mt = bid / 96, nt = bid - mt * 96;
  const int m0 = mt << 6, n0 = nt << 7;
  ZERO_ACC
  gemm_core64<false>(h2b + (size_t)m0 * HIDD, HIDD, wgu + (size_t)n0 * HIDD, HIDD,
                     0, HIDD, acc, As, Bsf);
  EPI_VARS
#pragma unroll
  for (int mi = 0; mi < 2; ++mi)
#pragma unroll
    for (int ni = 0; ni < 4; ++ni)
#pragma unroll
      for (int rr = 0; rr < 4; ++rr) {
        const int row = m0 + wr + mi * 16 + quad * 4 + rr;
        const int col = n0 + wc + ni * 16 + lrow;
        gu[(size_t)row * (2 * INTR) + col] = acc[mi][ni][rr];
      }
}

__global__ __launch_bounds__(256) void k_silu(const float* __restrict__ gu,
                                              unsigned short* __restrict__ actb) {
  const int j0 = (blockIdx.x * 256 + threadIdx.x) << 1;
  const int t = blockIdx.y;
  const float2 g = *reinterpret_cast<const float2*>(gu + (size_t)t * (2 * INTR) + j0);
  const float2 u = *reinterpret_cast<const float2*>(gu + (size_t)t * (2 * INTR) + INTR + j0);
  const float a0 = g.x / (1.f + __expf(-g.x)) * u.x;
  const float a1 = g.y / (1.f + __expf(-g.y)) * u.y;
  *reinterpret_cast<unsigned int*>(actb + (size_t)t * INTR + j0) = f2b2(a0, a1);
}

__global__ __launch_bounds__(256) void k_gemm_down(const unsigned short* __restrict__ actb,
                                                   const float* __restrict__ wdn,
                                                   float* __restrict__ Pdn) {
  __shared__ unsigned short As[64 * 32];
  __shared__ float Bsf[128 * 32];
  const int bid = blockIdx.x;       // 1024 = 8 mt x (16 nt x 8 s)
  const int mt = bid >> 7, gid = bid & 127;
  const int nt = gid >> 3, s = gid & 7;
  const int m0 = mt << 6, n0 = nt << 7;
  ZERO_ACC
  gemm_core64<false>(actb + (size_t)m0 * INTR, INTR, wdn + (size_t)n0 * INTR, INTR,
                     s * 768, s * 768 + 768, acc, As, Bsf);
  EPI_VARS
  float* out = Pdn + (size_t)s * (TT * HIDD);
#pragma unroll
  for (int mi = 0; mi < 2; ++mi)
#pragma unroll
    for (int ni = 0; ni < 4; ++ni)
#pragma unroll
      for (int rr = 0; rr < 4; ++rr) {
        const int row = m0 + wr + mi * 16 + quad * 4 + rr;
        const int col = n0 + wc + ni * 16 + lrow;
        out[(size_t)row * HIDD + col] = acc[mi][ni][rr];
      }
}

__global__ __launch_bounds__(256) void k_final(const float* __restrict__ hidden,
                                               const float* __restrict__ Pdn,
                                               float* __restrict__ out0) {
  __shared__ float tile[32][33];
  const int c0 = blockIdx.x << 5, t0 = blockIdx.y << 5;
  const int tx = threadIdx.x & 31, ty0 = (threadIdx.x >> 5) << 2;
#pragma unroll
  for (int i = 0; i < 4; ++i) {
    const int t = t0 + ty0 + i;
    const size_t idx = (size_t)t * HIDD + c0 + tx;
    float a = hidden[idx];
#pragma unroll
    for (int sp = 0; sp < 8; ++sp) a += Pdn[idx + (size_t)sp * (TT * HIDD)];
    tile[ty0 + i][tx] = a;
  }
  __syncthreads();
#pragma unroll
  for (int i = 0; i < 4; ++i)
    out0[(size_t)(c0 + ty0 + i) * TT + t0 + tx] = tile[tx][ty0 + i];
}

extern "C" void kernel_launch(void* const* d_in, const int* in_sizes, int n_in,
                              void* d_out, int out_size, void* d_ws, size_t ws_size,
                              hipStream_t stream) {
  const float* conv   = (const float*)d_in[0];
  const float* cosb   = (const float*)d_in[1];
  const float* sinb   = (const float*)d_in[2];
  const float* kcache = (const float*)d_in[5];
  const float* vcache = (const float*)d_in[6];
  const float* wq  = (const float*)d_in[7];
  const float* wk  = (const float*)d_in[8];
  const float* wv  = (const float*)d_in[9];
  const float* wo  = (const float*)d_in[10];
  const float* ln1 = (const float*)d_in[11];
  const float* ln2 = (const float*)d_in[12];
  const float* qnw = (const float*)d_in[13];
  const float* knw = (const float*)d_in[14];
  const float* wgu = (const float*)d_in[15];
  const float* wdn = (const float*)d_in[16];

  float* ws = (float*)d_ws;
  // layout (floats): total 14,155,776 f = 56.6 MB (< 71.3 MB proven)
  float* xb = ws + 0;                                      // 1,048,576
  unsigned short* h1b  = (unsigned short*)(ws + 1048576);  // 524,288 f ; later o_inb
  unsigned short* o_inb = h1b;
  unsigned short* h2b  = (unsigned short*)(ws + 1572864);  // 524,288 f
  float* hidden = ws + 2097152;                            // 1,048,576
  unsigned short* qb  = (unsigned short*)(ws + 3145728);   // 16*512*128 us
  unsigned short* kb  = qb + 1048576;                      // 8*512*128 us
  unsigned short* vtb = kb + 524288;                       // 8*128*512 us (d-major)
  unsigned short* actb = (unsigned short*)(ws + 4194304);  // 512*6144 us
  float* R   = ws + 5767168;                               // 8,388,608 f shared region
  float* Pq  = R;                                          //  qkv:   4 x 2,097,152
  unsigned short* Pb = (unsigned short*)R;                 //  attn:  2,097,152 f-slots
  float* sc  = R + 2097152;                                //  attn:  4,194,304
  float* Ppv = R + 2097152;                                //  pv:    4 x 1,048,576
  float* Po  = R;                                          //  o:     8 x 1,048,576
  float* gu  = R;                                          //  mlp:   6,291,456
  float* Pdn = R;                                          //  down:  8 x 1,048,576

  float* out0 = (float*)d_out;   // (HID, T)
  float* kout = out0 + 1048576;  // (NKV, SEQ, D)
  float* vout = kout + 4194304;  // (NKV, SEQ, D)

  k_rms1<<<16, 1024, 0, stream>>>(conv, ln1, xb, h1b);
  k_gemm_qkv<<<1024, 256, 0, stream>>>(h1b, wq, wk, wv, Pq);
  k_rope<<<dim3(NH + 2 * NKV, TT), 128, 0, stream>>>(Pq, cosb, sinb, qnw, knw, qb, kb, vtb, kout, vout);
  k_tail<<<4096, 256, 0, stream>>>(kcache, vcache, kout, vout);
  k_scores<<<dim3(8, 4, NH), 256, 0, stream>>>(qb, kb, sc);
  k_softmax<<<NH * TT, 256, 0, stream>>>(sc, Pb);
  k_pv<<<dim3(8, NH, 4), 256, 0, stream>>>(Pb, vtb, Ppv);
  k_red_pv<<<1024, 256, 0, stream>>>(Ppv, o_inb);
  k_gemm_o<<<1024, 256, 0, stream>>>(o_inb, wo, Po);
  k_rms2<<<TT, 256, 0, stream>>>(xb, Po, ln2, hidden, h2b);
  k_gemm_gu<<<768, 256, 0, stream>>>(h2b, wgu, gu);
  k_silu<<<dim3(12, TT), 256, 0, stream>>>(gu, actb);
  k_gemm_down<<<1024, 256, 0, stream>>>(actb, wdn, Pdn);
  k_final<<<dim3(HIDD / 32, TT / 32), 256, 0, stream>>>(hidden, Pdn, out0);
}